// Round 2
// baseline (544.796 us; speedup 1.0000x reference)
//
#include <hip/hip_runtime.h>
#include <hip/hip_bf16.h>
#include <stdint.h>

#define B_   64
#define T_   2048
#define DQ_  1024
#define A_   128
#define E_   512
#define NF_  32
#define KW_  31
#define PAD_ 15
#define M_   (B_*T_)      // 131072
#define KE_  544          // 512 + 32

typedef __attribute__((ext_vector_type(8))) short bf16x8;
typedef __attribute__((ext_vector_type(4))) float f32x4;

// workspace layout (bytes)
#define OFF_WCAT 0            // 128*544*2  = 139264
#define OFF_Q    139264       // 64*128*4   = 32768
#define OFF_EN   172032       // 131072*4   = 524288
#define OFF_CF   696320       // 131072*32*4 = 16777216  (end ~17.5 MB)

__device__ inline ushort f2bf(float f) {
  uint32_t u = __float_as_uint(f);
  u += 0x7fffu + ((u >> 16) & 1u);
  return (ushort)(u >> 16);
}
__device__ inline uint32_t pkbf(float a, float b) {
  uint32_t x = __float_as_uint(a), y = __float_as_uint(b);
  x += 0x7fffu + ((x >> 16) & 1u);
  y += 0x7fffu + ((y >> 16) & 1u);
  return (x >> 16) | (y & 0xffff0000u);
}
__device__ inline float tanh_fast(float x) {
  float cx = fminf(fmaxf(x, -15.f), 15.f);
  float e = __expf(2.f * cx);
  return (e - 1.f) / (e + 1.f);
}

// ---- prep: Wcat = bf16([W_memory | W_loc]) : [128][544] ----
__global__ void prep_wcat(const float* __restrict__ wmem, const float* __restrict__ wloc,
                          ushort* __restrict__ wcat) {
  int a = blockIdx.x, tid = threadIdx.x;
  for (int c = tid; c < E_; c += 256) wcat[a*KE_ + c] = f2bf(wmem[a*E_ + c]);
  if (tid < NF_) wcat[a*KE_ + E_ + tid] = f2bf(wloc[a*NF_ + tid]);
}

// ---- prep: q[b][a] = query[b] . W_query[a] ----
__global__ void prep_q(const float* __restrict__ query, const float* __restrict__ wq,
                       float* __restrict__ q) {
  __shared__ float qS[DQ_];
  int b = blockIdx.x, tid = threadIdx.x;  // 128 threads
  for (int d = tid; d < DQ_; d += 128) qS[d] = query[b*DQ_ + d];
  __syncthreads();
  const float* wr = wq + (long)tid*DQ_;
  float s = 0.f;
  for (int d = 0; d < DQ_; d += 4) {
    float4 w4 = *(const float4*)(wr + d);
    s = fmaf(qS[d],   w4.x, s); s = fmaf(qS[d+1], w4.y, s);
    s = fmaf(qS[d+2], w4.z, s); s = fmaf(qS[d+3], w4.w, s);
  }
  q[b*A_ + tid] = s;
}

// ---- conv features: convf[b*T+t][f] = sum_{c,k} aw[b,c,t+k-15]*cw[f,c,k] ----
__global__ void conv_kernel(const float* __restrict__ aw, const float* __restrict__ cw,
                            float* __restrict__ convf) {
  __shared__ float awS[2][288];
  __shared__ float cwS[NF_*2*KW_];   // 1984
  int bid = blockIdx.x;
  int b = bid >> 3, tc = bid & 7, t0 = tc*256;
  int tid = threadIdx.x;
  for (int i = tid; i < 286; i += 256) {
    int g = t0 + i - PAD_;
    bool ok = (g >= 0) && (g < T_);
    awS[0][i] = ok ? aw[(long)b*2*T_ + g]       : 0.f;
    awS[1][i] = ok ? aw[(long)b*2*T_ + T_ + g]  : 0.f;
  }
  for (int i = tid; i < NF_*2*KW_; i += 256) cwS[i] = cw[i];
  __syncthreads();
  float* outp = convf + ((long)(b*T_ + t0 + tid))*NF_;
  #pragma unroll 1
  for (int f = 0; f < NF_; ++f) {
    const float* c0 = &cwS[f*2*KW_];
    float s = 0.f;
    #pragma unroll
    for (int k = 0; k < KW_; ++k) {
      s = fmaf(awS[0][tid + k], c0[k],       s);
      s = fmaf(awS[1][tid + k], c0[KW_ + k], s);
    }
    outp[f] = s;
  }
}

// ---- energies: e[row] = sum_a v[a]*tanh(q[b,a] + [mem|convf]@Wcat^T) ----
// tile 128 rows x 128 cols, BK=64 (8 steps over memory) + 1 half step (convf)
__launch_bounds__(256)
__global__ void energy_kernel(const float* __restrict__ memf, const float* __restrict__ convf,
                              const ushort* __restrict__ wcat, const float* __restrict__ q,
                              const float* __restrict__ vvec, float* __restrict__ energies) {
  __shared__ uint4 As4[1024];   // 128 rows x 8 chunks(16B) bf16, XOR-swizzled
  __shared__ uint4 Bs4[1024];
  __shared__ float epS[256];
  const int tid  = threadIdx.x;
  const int lane = tid & 63, wid = tid >> 6;
  const int wm = wid >> 1, wn = wid & 1;       // 2x2 waves of 64x64
  const int fr = lane & 15, fk = lane >> 4;
  const long row0 = (long)blockIdx.x * 128;
  const int b = (int)(row0 >> 11);

  f32x4 acc[4][4];
  #pragma unroll
  for (int m = 0; m < 4; ++m)
    #pragma unroll
    for (int n = 0; n < 4; ++n) acc[m][n] = (f32x4){0.f,0.f,0.f,0.f};

  for (int kt = 0; kt < 9; ++kt) {
    __syncthreads();
    if (kt < 8) {
      const int k0 = kt*64;
      // stage A: memory f32 -> bf16, ds_write swizzled
      #pragma unroll
      for (int i = 0; i < 4; ++i) {
        int c = i*256 + tid;
        int r = c >> 3, cl = c & 7;
        const float* src = memf + (row0 + r)*E_ + k0 + cl*8;
        float4 x = *(const float4*)src;
        float4 y = *(const float4*)(src + 4);
        uint4 p = { pkbf(x.x,x.y), pkbf(x.z,x.w), pkbf(y.x,y.y), pkbf(y.z,y.w) };
        As4[r*8 + (cl ^ (r & 7))] = p;
      }
      // stage B: bf16 Wcat via global_load_lds, linear dest + pre-swizzled source
      #pragma unroll
      for (int i = 0; i < 4; ++i) {
        int c = i*256 + tid;
        int r = c >> 3, cd = c & 7;
        int cl = cd ^ (r & 7);
        const ushort* src = wcat + r*KE_ + k0 + cl*8;
        __builtin_amdgcn_global_load_lds((const __attribute__((address_space(1))) void*)src,
                                         (__attribute__((address_space(3))) void*)(Bs4 + c),
                                         16, 0, 0);
      }
    } else {
      // last step: K-chunk 512..543 from convf / Wcat tail (32 cols)
      #pragma unroll
      for (int i = 0; i < 2; ++i) {
        int c = i*256 + tid;
        int r = c >> 2, cl = c & 3;
        const float* src = convf + (row0 + r)*NF_ + cl*8;
        float4 x = *(const float4*)src;
        float4 y = *(const float4*)(src + 4);
        uint4 p = { pkbf(x.x,x.y), pkbf(x.z,x.w), pkbf(y.x,y.y), pkbf(y.z,y.w) };
        As4[r*8 + (cl ^ (r & 7))] = p;
      }
      #pragma unroll
      for (int i = 0; i < 2; ++i) {
        int c = i*256 + tid;
        int r = c >> 2, cl = c & 3;
        uint4 w = *(const uint4*)(wcat + r*KE_ + E_ + cl*8);
        Bs4[r*8 + (cl ^ (r & 7))] = w;
      }
    }
    __syncthreads();
    const ushort* As = (const ushort*)As4;
    const ushort* Bs = (const ushort*)Bs4;
    const int nkk = (kt < 8) ? 2 : 1;
    for (int kk = 0; kk < nkk; ++kk) {
      bf16x8 af[4], bfr[4];
      const int clk = kk*4 + fk;
      #pragma unroll
      for (int m = 0; m < 4; ++m) {
        int r = wm*64 + m*16 + fr;
        af[m] = *(const bf16x8*)(As + r*64 + (clk ^ (r & 7))*8);
      }
      #pragma unroll
      for (int n = 0; n < 4; ++n) {
        int r = wn*64 + n*16 + fr;
        bfr[n] = *(const bf16x8*)(Bs + r*64 + (clk ^ (r & 7))*8);
      }
      #pragma unroll
      for (int m = 0; m < 4; ++m)
        #pragma unroll
        for (int n = 0; n < 4; ++n)
          acc[m][n] = __builtin_amdgcn_mfma_f32_16x16x32_bf16(af[m], bfr[n], acc[m][n], 0, 0, 0);
    }
  }

  // epilogue: v * tanh(acc + q), reduce over a (cols)
  const float* qb = q + b*A_;
  float ep[4][4];
  #pragma unroll
  for (int m = 0; m < 4; ++m)
    #pragma unroll
    for (int r = 0; r < 4; ++r) ep[m][r] = 0.f;
  #pragma unroll
  for (int n = 0; n < 4; ++n) {
    int col = wn*64 + n*16 + fr;
    float qa = qb[col];
    float va = vvec[col];
    #pragma unroll
    for (int m = 0; m < 4; ++m)
      #pragma unroll
      for (int r = 0; r < 4; ++r)
        ep[m][r] = fmaf(va, tanh_fast(acc[m][n][r] + qa), ep[m][r]);
  }
  #pragma unroll
  for (int m = 0; m < 4; ++m)
    #pragma unroll
    for (int r = 0; r < 4; ++r) {
      float v = ep[m][r];
      v += __shfl_xor(v, 1); v += __shfl_xor(v, 2);
      v += __shfl_xor(v, 4); v += __shfl_xor(v, 8);
      ep[m][r] = v;
    }
  if (fr == 0) {
    #pragma unroll
    for (int m = 0; m < 4; ++m)
      #pragma unroll
      for (int r = 0; r < 4; ++r)
        epS[wn*128 + wm*64 + m*16 + fk*4 + r] = ep[m][r];
  }
  __syncthreads();
  if (tid < 128) energies[row0 + tid] = epS[tid] + epS[128 + tid];
}

// ---- softmax over T per batch ----
__global__ void softmax_kernel(const float* __restrict__ energies, float* __restrict__ outw) {
  __shared__ float redm[4], reds[4];
  int b = blockIdx.x, tid = threadIdx.x;
  int lane = tid & 63, wid = tid >> 6;
  const float* e = energies + (long)b*T_;
  float v[8];
  float m = -1e30f;
  #pragma unroll
  for (int i = 0; i < 8; ++i) { v[i] = e[tid + i*256]; m = fmaxf(m, v[i]); }
  #pragma unroll
  for (int o = 32; o > 0; o >>= 1) m = fmaxf(m, __shfl_xor(m, o));
  if (lane == 0) redm[wid] = m;
  __syncthreads();
  m = fmaxf(fmaxf(redm[0], redm[1]), fmaxf(redm[2], redm[3]));
  float s = 0.f;
  #pragma unroll
  for (int i = 0; i < 8; ++i) { v[i] = __expf(v[i] - m); s += v[i]; }
  #pragma unroll
  for (int o = 32; o > 0; o >>= 1) s += __shfl_xor(s, o);
  if (lane == 0) reds[wid] = s;
  __syncthreads();
  s = reds[0] + reds[1] + reds[2] + reds[3];
  float inv = 1.f / s;
  #pragma unroll
  for (int i = 0; i < 8; ++i) outw[(long)b*T_ + tid + i*256] = v[i] * inv;
}

// ---- context: ctx[b][e] = sum_t w[b,t]*mem[b,t,e] ----
__global__ void context_kernel(const float* __restrict__ memf, const float* __restrict__ w,
                               float* __restrict__ ctx) {
  int bid = blockIdx.x;
  int b = bid >> 3, tc = bid & 7;
  int tid = threadIdx.x;
  const float* wrow  = w + (long)b*T_ + tc*256;
  const float* mbase = memf + ((long)b*T_ + tc*256)*E_;
  float a0 = 0.f, a1 = 0.f;
  #pragma unroll 4
  for (int t = 0; t < 256; ++t) {
    float wt = wrow[t];
    const float* mr = mbase + (long)t*E_;
    a0 = fmaf(wt, mr[tid],       a0);
    a1 = fmaf(wt, mr[tid + 256], a1);
  }
  atomicAdd(&ctx[b*E_ + tid],       a0);
  atomicAdd(&ctx[b*E_ + tid + 256], a1);
}

extern "C" void kernel_launch(void* const* d_in, const int* in_sizes, int n_in,
                              void* d_out, int out_size, void* d_ws, size_t ws_size,
                              hipStream_t stream) {
  const float* query  = (const float*)d_in[0];
  const float* memory = (const float*)d_in[1];
  const float* awcat  = (const float*)d_in[2];
  const float* wq     = (const float*)d_in[3];
  const float* wmem   = (const float*)d_in[4];
  const float* convw  = (const float*)d_in[5];
  const float* wloc   = (const float*)d_in[6];
  const float* vvec   = (const float*)d_in[7];

  char* ws = (char*)d_ws;
  ushort* wcat    = (ushort*)(ws + OFF_WCAT);
  float*  qproj   = (float*)(ws + OFF_Q);
  float*  energies= (float*)(ws + OFF_EN);
  float*  convf   = (float*)(ws + OFF_CF);

  float* ctx  = (float*)d_out;              // [64][512]
  float* outw = (float*)d_out + B_*E_;      // [64][2048]

  hipMemsetAsync(ctx, 0, B_*E_*sizeof(float), stream);
  prep_wcat<<<128, 256, 0, stream>>>(wmem, wloc, wcat);
  prep_q<<<64, 128, 0, stream>>>(query, wq, qproj);
  conv_kernel<<<512, 256, 0, stream>>>(awcat, convw, convf);
  energy_kernel<<<1024, 256, 0, stream>>>(memory, convf, wcat, qproj, vvec, energies);
  softmax_kernel<<<64, 256, 0, stream>>>(energies, outw);
  context_kernel<<<512, 256, 0, stream>>>(memory, outw, ctx);
}

// Round 3
// 534.873 us; speedup vs baseline: 1.0186x; 1.0186x over previous
//
#include <hip/hip_runtime.h>
#include <hip/hip_bf16.h>
#include <stdint.h>

#define B_   64
#define T_   2048
#define DQ_  1024
#define A_   128
#define E_   512
#define NF_  32
#define KW_  31
#define PAD_ 15
#define KE_  544          // 512 + 32

typedef __attribute__((ext_vector_type(8))) short bf16x8;
typedef __attribute__((ext_vector_type(4))) float f32x4;

// workspace layout (bytes)
#define OFF_WCAT 0            // 128*544*2  = 139264
#define OFF_Q    139264       // 64*128*4   = 32768
#define OFF_EN   172032       // 131072*4   = 524288
#define OFF_ST   696320       // 1024*2*4   = 8192

__device__ inline ushort f2bf(float f) {
  uint32_t u = __float_as_uint(f);
  u += 0x7fffu + ((u >> 16) & 1u);
  return (ushort)(u >> 16);
}
__device__ inline uint32_t pkbf(float a, float b) {
  uint32_t x = __float_as_uint(a), y = __float_as_uint(b);
  x += 0x7fffu + ((x >> 16) & 1u);
  y += 0x7fffu + ((y >> 16) & 1u);
  return (x >> 16) | (y & 0xffff0000u);
}
__device__ inline float tanh_fast(float x) {
  float cx = fminf(fmaxf(x, -15.f), 15.f);
  float e = __expf(2.f * cx);
  return (e - 1.f) / (e + 1.f);
}

// ---- prep: Wcat = bf16([W_memory | W_loc]) : [128][544] ----
__global__ void prep_wcat(const float* __restrict__ wmem, const float* __restrict__ wloc,
                          ushort* __restrict__ wcat) {
  int a = blockIdx.x, tid = threadIdx.x;
  for (int c = tid; c < E_; c += 256) wcat[a*KE_ + c] = f2bf(wmem[a*E_ + c]);
  if (tid < NF_) wcat[a*KE_ + E_ + tid] = f2bf(wloc[a*NF_ + tid]);
}

// ---- prep: q[b][a] = query[b] . W_query[a] ----
__global__ void prep_q(const float* __restrict__ query, const float* __restrict__ wq,
                       float* __restrict__ q) {
  __shared__ float qS[DQ_];
  int b = blockIdx.x, tid = threadIdx.x;  // 128 threads
  for (int d = tid; d < DQ_; d += 128) qS[d] = query[b*DQ_ + d];
  __syncthreads();
  const float* wr = wq + (long)tid*DQ_;
  float s = 0.f;
  for (int d = 0; d < DQ_; d += 4) {
    float4 w4 = *(const float4*)(wr + d);
    s = fmaf(qS[d],   w4.x, s); s = fmaf(qS[d+1], w4.y, s);
    s = fmaf(qS[d+2], w4.z, s); s = fmaf(qS[d+3], w4.w, s);
  }
  q[b*A_ + tid] = s;
}

// ---- energies + per-block softmax stats; conv fused into last K-step ----
// tile 128 rows x 128 cols, BK=64 (8 steps over memory) + 1 half step (conv feats)
__launch_bounds__(256)
__global__ void energy_kernel(const float* __restrict__ memf, const float* __restrict__ aw,
                              const float* __restrict__ cw, const ushort* __restrict__ wcat,
                              const float* __restrict__ q, const float* __restrict__ vvec,
                              float* __restrict__ energies, float* __restrict__ stats) {
  __shared__ uint4 As4[1024];   // 128 rows x 8 chunks(16B) bf16, XOR-swizzled
  __shared__ uint4 Bs4[1024];
  __shared__ float epS[256];
  __shared__ float awS[2][160]; // aw window [t0-15, t0+142]
  __shared__ float cwS[NF_*2*KW_];   // 1984
  __shared__ float redS[4];
  const int tid  = threadIdx.x;
  const int lane = tid & 63, wid = tid >> 6;
  const int wm = wid >> 1, wn = wid & 1;       // 2x2 waves of 64x64
  const int fr = lane & 15, fk = lane >> 4;
  const long row0 = (long)blockIdx.x * 128;
  const int b = (int)(row0 >> 11);
  const int t0 = (int)(row0 & (T_-1));

  // stage conv inputs (used only at kt==8; many barriers in between)
  for (int i = tid; i < 158; i += 256) {
    int g = t0 + i - PAD_;
    bool ok = (g >= 0) && (g < T_);
    awS[0][i] = ok ? aw[(long)b*2*T_ + g]      : 0.f;
    awS[1][i] = ok ? aw[(long)b*2*T_ + T_ + g] : 0.f;
  }
  for (int i = tid; i < NF_*2*KW_; i += 256) cwS[i] = cw[i];

  f32x4 acc[4][4];
  #pragma unroll
  for (int m = 0; m < 4; ++m)
    #pragma unroll
    for (int n = 0; n < 4; ++n) acc[m][n] = (f32x4){0.f,0.f,0.f,0.f};

  for (int kt = 0; kt < 9; ++kt) {
    __syncthreads();
    if (kt < 8) {
      const int k0 = kt*64;
      // stage A: memory f32 -> bf16, ds_write swizzled
      #pragma unroll
      for (int i = 0; i < 4; ++i) {
        int c = i*256 + tid;
        int r = c >> 3, cl = c & 7;
        const float* src = memf + (row0 + r)*E_ + k0 + cl*8;
        float4 x = *(const float4*)src;
        float4 y = *(const float4*)(src + 4);
        uint4 p = { pkbf(x.x,x.y), pkbf(x.z,x.w), pkbf(y.x,y.y), pkbf(y.z,y.w) };
        As4[r*8 + (cl ^ (r & 7))] = p;
      }
      // stage B: bf16 Wcat via global_load_lds, linear dest + pre-swizzled source
      #pragma unroll
      for (int i = 0; i < 4; ++i) {
        int c = i*256 + tid;
        int r = c >> 3, cd = c & 7;
        int cl = cd ^ (r & 7);
        const ushort* src = wcat + r*KE_ + k0 + cl*8;
        __builtin_amdgcn_global_load_lds((const __attribute__((address_space(1))) void*)src,
                                         (__attribute__((address_space(3))) void*)(Bs4 + c),
                                         16, 0, 0);
      }
    } else {
      // last step: K-chunk 512..543 = conv features, computed inline from awS/cwS
      #pragma unroll
      for (int i = 0; i < 2; ++i) {
        int c = i*256 + tid;
        int r = c >> 2, cl = c & 3;      // row r, features cl*8..cl*8+7
        float f[8];
        #pragma unroll
        for (int j = 0; j < 8; ++j) {
          const float* c0 = &cwS[(cl*8 + j)*2*KW_];
          float s = 0.f;
          #pragma unroll
          for (int k = 0; k < KW_; ++k) {
            s = fmaf(awS[0][r + k], c0[k],       s);
            s = fmaf(awS[1][r + k], c0[KW_ + k], s);
          }
          f[j] = s;
        }
        uint4 p = { pkbf(f[0],f[1]), pkbf(f[2],f[3]), pkbf(f[4],f[5]), pkbf(f[6],f[7]) };
        As4[r*8 + (cl ^ (r & 7))] = p;
      }
      #pragma unroll
      for (int i = 0; i < 2; ++i) {
        int c = i*256 + tid;
        int r = c >> 2, cl = c & 3;
        uint4 w = *(const uint4*)(wcat + r*KE_ + E_ + cl*8);
        Bs4[r*8 + (cl ^ (r & 7))] = w;
      }
    }
    __syncthreads();
    const ushort* As = (const ushort*)As4;
    const ushort* Bs = (const ushort*)Bs4;
    const int nkk = (kt < 8) ? 2 : 1;
    for (int kk = 0; kk < nkk; ++kk) {
      bf16x8 af[4], bfr[4];
      const int clk = kk*4 + fk;
      #pragma unroll
      for (int m = 0; m < 4; ++m) {
        int r = wm*64 + m*16 + fr;
        af[m] = *(const bf16x8*)(As + r*64 + (clk ^ (r & 7))*8);
      }
      #pragma unroll
      for (int n = 0; n < 4; ++n) {
        int r = wn*64 + n*16 + fr;
        bfr[n] = *(const bf16x8*)(Bs + r*64 + (clk ^ (r & 7))*8);
      }
      #pragma unroll
      for (int m = 0; m < 4; ++m)
        #pragma unroll
        for (int n = 0; n < 4; ++n)
          acc[m][n] = __builtin_amdgcn_mfma_f32_16x16x32_bf16(af[m], bfr[n], acc[m][n], 0, 0, 0);
    }
  }

  // epilogue: v * tanh(acc + q), reduce over a (cols)
  const float* qb = q + b*A_;
  float ep[4][4];
  #pragma unroll
  for (int m = 0; m < 4; ++m)
    #pragma unroll
    for (int r = 0; r < 4; ++r) ep[m][r] = 0.f;
  #pragma unroll
  for (int n = 0; n < 4; ++n) {
    int col = wn*64 + n*16 + fr;
    float qa = qb[col];
    float va = vvec[col];
    #pragma unroll
    for (int m = 0; m < 4; ++m)
      #pragma unroll
      for (int r = 0; r < 4; ++r)
        ep[m][r] = fmaf(va, tanh_fast(acc[m][n][r] + qa), ep[m][r]);
  }
  #pragma unroll
  for (int m = 0; m < 4; ++m)
    #pragma unroll
    for (int r = 0; r < 4; ++r) {
      float v = ep[m][r];
      v += __shfl_xor(v, 1); v += __shfl_xor(v, 2);
      v += __shfl_xor(v, 4); v += __shfl_xor(v, 8);
      ep[m][r] = v;
    }
  if (fr == 0) {
    #pragma unroll
    for (int m = 0; m < 4; ++m)
      #pragma unroll
      for (int r = 0; r < 4; ++r)
        epS[wn*128 + wm*64 + m*16 + fk*4 + r] = ep[m][r];
  }
  __syncthreads();
  // energies + per-block (max, sumexp) stats
  float e = -1e30f;
  if (tid < 128) {
    e = epS[tid] + epS[128 + tid];
    energies[row0 + tid] = e;
  }
  float mx = e;
  #pragma unroll
  for (int o = 32; o > 0; o >>= 1) mx = fmaxf(mx, __shfl_xor(mx, o));
  if (lane == 0) redS[wid] = mx;
  __syncthreads();
  mx = fmaxf(fmaxf(redS[0], redS[1]), fmaxf(redS[2], redS[3]));
  float sx = (tid < 128) ? __expf(e - mx) : 0.f;
  #pragma unroll
  for (int o = 32; o > 0; o >>= 1) sx += __shfl_xor(sx, o);
  __syncthreads();
  if (lane == 0) redS[wid] = sx;
  __syncthreads();
  if (tid == 0) {
    stats[2*blockIdx.x]     = mx;
    stats[2*blockIdx.x + 1] = redS[0] + redS[1] + redS[2] + redS[3];
  }
}

// ---- softmax finalize + context: 16 blocks per batch, 128 rows each ----
__launch_bounds__(256)
__global__ void smctx_kernel(const float* __restrict__ memf, const float* __restrict__ energies,
                             const float* __restrict__ stats, float* __restrict__ outw,
                             float* __restrict__ ctx) {
  __shared__ float wS[128];
  const int blk = blockIdx.x;          // 1024
  const int b = blk >> 4;
  const int t0 = (blk & 15) * 128;
  const int tid = threadIdx.x;
  // batch softmax normalization from 16 block-stats
  float M = -1e30f;
  #pragma unroll
  for (int j = 0; j < 16; ++j) M = fmaxf(M, stats[2*(b*16 + j)]);
  float Z = 0.f;
  #pragma unroll
  for (int j = 0; j < 16; ++j) Z += stats[2*(b*16 + j) + 1] * __expf(stats[2*(b*16 + j)] - M);
  const float invZ = 1.f / Z;
  if (tid < 128) {
    float w = __expf(energies[(long)b*T_ + t0 + tid] - M) * invZ;
    outw[(long)b*T_ + t0 + tid] = w;
    wS[tid] = w;
  }
  __syncthreads();
  // context partial over 128 rows, 2 cols per thread
  const float* mb = memf + ((long)b*T_ + t0)*E_;
  float ax = 0.f, ay = 0.f;
  #pragma unroll 8
  for (int t = 0; t < 128; ++t) {
    float wt = wS[t];
    float2 m2 = *(const float2*)(mb + (long)t*E_ + tid*2);
    ax = fmaf(wt, m2.x, ax);
    ay = fmaf(wt, m2.y, ay);
  }
  atomicAdd(&ctx[b*E_ + tid*2],     ax);
  atomicAdd(&ctx[b*E_ + tid*2 + 1], ay);
}

extern "C" void kernel_launch(void* const* d_in, const int* in_sizes, int n_in,
                              void* d_out, int out_size, void* d_ws, size_t ws_size,
                              hipStream_t stream) {
  const float* query  = (const float*)d_in[0];
  const float* memory = (const float*)d_in[1];
  const float* awcat  = (const float*)d_in[2];
  const float* wq     = (const float*)d_in[3];
  const float* wmem   = (const float*)d_in[4];
  const float* convw  = (const float*)d_in[5];
  const float* wloc   = (const float*)d_in[6];
  const float* vvec   = (const float*)d_in[7];

  char* ws = (char*)d_ws;
  ushort* wcat    = (ushort*)(ws + OFF_WCAT);
  float*  qproj   = (float*)(ws + OFF_Q);
  float*  energies= (float*)(ws + OFF_EN);
  float*  stats   = (float*)(ws + OFF_ST);

  float* ctx  = (float*)d_out;              // [64][512]
  float* outw = (float*)d_out + B_*E_;      // [64][2048]

  hipMemsetAsync(ctx, 0, B_*E_*sizeof(float), stream);
  prep_wcat<<<128, 256, 0, stream>>>(wmem, wloc, wcat);
  prep_q<<<64, 128, 0, stream>>>(query, wq, qproj);
  energy_kernel<<<1024, 256, 0, stream>>>(memory, awcat, convw, wcat, qproj, vvec,
                                          energies, stats);
  smctx_kernel<<<1024, 256, 0, stream>>>(memory, energies, stats, outw, ctx);
}

// Round 6
// 506.019 us; speedup vs baseline: 1.0766x; 1.0570x over previous
//
#include <hip/hip_runtime.h>
#include <hip/hip_bf16.h>
#include <stdint.h>

#define B_   64
#define T_   2048
#define DQ_  1024
#define A_   128
#define E_   512
#define NF_  32
#define KW_  31
#define PAD_ 15
#define KE_  544          // 512 + 32

typedef __attribute__((ext_vector_type(8))) short bf16x8;
typedef __attribute__((ext_vector_type(4))) float f32x4;

// workspace layout (bytes, 64B-aligned)
#define OFF_WCAT 0            // 128*544*2   = 139264
#define OFF_Q    139264       // 64*128*4    = 32768
#define OFF_EN   172032       // 131072*4    = 524288
#define OFF_ST   696320       // 1024*2*4    = 8192
#define OFF_CF   704512       // 131072*32*2 = 8388608   (end ~9.1 MB)

__device__ inline ushort f2bf(float f) {
  uint32_t u = __float_as_uint(f);
  u += 0x7fffu + ((u >> 16) & 1u);
  return (ushort)(u >> 16);
}
__device__ inline uint32_t pkbf(float a, float b) {
  uint32_t x = __float_as_uint(a), y = __float_as_uint(b);
  x += 0x7fffu + ((x >> 16) & 1u);
  y += 0x7fffu + ((y >> 16) & 1u);
  return (x >> 16) | (y & 0xffff0000u);
}
__device__ inline float tanh_fast(float x) {
  float cx = fminf(fmaxf(x, -15.f), 15.f);
  float e = __expf(2.f * cx);
  return (e - 1.f) / (e + 1.f);
}

// ---- prep: Wcat = bf16([W_memory | W_loc]) : [128 cols][544 k] ----
__global__ void prep_wcat(const float* __restrict__ wmem, const float* __restrict__ wloc,
                          ushort* __restrict__ wcat) {
  int a = blockIdx.x, tid = threadIdx.x;
  for (int c = tid; c < E_; c += 256) wcat[a*KE_ + c] = f2bf(wmem[a*E_ + c]);
  if (tid < NF_) wcat[a*KE_ + E_ + tid] = f2bf(wloc[a*NF_ + tid]);
}

// ---- prep: q[b][a] = query[b] . W_query[a] ----
__global__ void prep_q(const float* __restrict__ query, const float* __restrict__ wq,
                       float* __restrict__ q) {
  __shared__ float qS[DQ_];
  int b = blockIdx.x, tid = threadIdx.x;  // 128 threads
  for (int d = tid; d < DQ_; d += 128) qS[d] = query[b*DQ_ + d];
  __syncthreads();
  const float* wr = wq + (long)tid*DQ_;
  float s = 0.f;
  for (int d = 0; d < DQ_; d += 4) {
    float4 w4 = *(const float4*)(wr + d);
    s = fmaf(qS[d],   w4.x, s); s = fmaf(qS[d+1], w4.y, s);
    s = fmaf(qS[d+2], w4.z, s); s = fmaf(qS[d+3], w4.w, s);
  }
  q[b*A_ + tid] = s;
}

// ---- conv features -> bf16 [B*T][32], coalesced uint4 stores ----
// grid 2048: 64 rows/block; thread (r=tid>>2, c=tid&3) computes feats c*8..c*8+7
__global__ void conv_kernel(const float* __restrict__ aw, const float* __restrict__ cw,
                            ushort* __restrict__ convf) {
  __shared__ float awS[2][96];           // window [t0-15, t0+78]
  __shared__ float cwS[NF_*2*KW_];       // 1984
  const int blk = blockIdx.x;
  const int b = blk >> 5, t0 = (blk & 31) * 64;
  const int tid = threadIdx.x;
  const int r = tid >> 2, c = tid & 3;
  for (int i = tid; i < 94; i += 256) {
    int g = t0 + i - PAD_;
    bool ok = (g >= 0) && (g < T_);
    awS[0][i] = ok ? aw[(long)b*2*T_ + g]      : 0.f;
    awS[1][i] = ok ? aw[(long)b*2*T_ + T_ + g] : 0.f;
  }
  for (int i = tid; i < NF_*2*KW_; i += 256) cwS[i] = cw[i];
  __syncthreads();
  float f[8];
  #pragma unroll
  for (int j = 0; j < 8; ++j) f[j] = 0.f;
  #pragma unroll
  for (int k = 0; k < KW_; ++k) {
    float a0 = awS[0][r + k], a1 = awS[1][r + k];
    #pragma unroll
    for (int j = 0; j < 8; ++j) {
      const float* c0 = &cwS[(c*8 + j)*2*KW_];
      f[j] = fmaf(a0, c0[k], f[j]);
      f[j] = fmaf(a1, c0[KW_ + k], f[j]);
    }
  }
  uint4 p = { pkbf(f[0],f[1]), pkbf(f[2],f[3]), pkbf(f[4],f[5]), pkbf(f[6],f[7]) };
  uint4* out4 = (uint4*)convf;
  out4[(long)(b*T_ + t0 + r)*4 + c] = p;
}

// ---- energies + per-block softmax stats; barrier-free per-wave GEMM ----
// block = 4 waves x 32 rows = 128 rows; each wave: rows w*32.., all 128 cols
__launch_bounds__(256)
__global__ void energy_kernel(const float* __restrict__ memf, const ushort* __restrict__ convf,
                              const ushort* __restrict__ wcat, const float* __restrict__ q,
                              const float* __restrict__ vvec, float* __restrict__ energies,
                              float* __restrict__ stats) {
  __shared__ float epS[128];
  __shared__ float redS[4];
  const int tid  = threadIdx.x;
  const int lane = tid & 63, w = tid >> 6;
  const int fr = lane & 15, fk = lane >> 4;
  const long rowB = (long)blockIdx.x * 128;   // block's first row
  const long row0 = rowB + w*32;              // wave's first row
  const int b = (int)(rowB >> 11);

  f32x4 acc[2][8];
  #pragma unroll
  for (int m = 0; m < 2; ++m)
    #pragma unroll
    for (int n = 0; n < 8; ++n) acc[m][n] = (f32x4){0.f,0.f,0.f,0.f};

  const float*  a0p = memf + (row0 + fr)*E_;        // m=0 row
  const float*  a1p = memf + (row0 + 16 + fr)*E_;   // m=1 row
  const ushort* bp  = wcat + fr*KE_;                // + n*16*KE_

  #pragma unroll 1
  for (int kt = 0; kt < 8; ++kt) {
    #pragma unroll
    for (int kk = 0; kk < 2; ++kk) {
      const int k = kt*64 + kk*32 + fk*8;
      float4 x0 = *(const float4*)(a0p + k);
      float4 y0 = *(const float4*)(a0p + k + 4);
      float4 x1 = *(const float4*)(a1p + k);
      float4 y1 = *(const float4*)(a1p + k + 4);
      bf16x8 am[2];
      { uint4 p0 = { pkbf(x0.x,x0.y), pkbf(x0.z,x0.w), pkbf(y0.x,y0.y), pkbf(y0.z,y0.w) };
        uint4 p1 = { pkbf(x1.x,x1.y), pkbf(x1.z,x1.w), pkbf(y1.x,y1.y), pkbf(y1.z,y1.w) };
        am[0] = *(bf16x8*)&p0; am[1] = *(bf16x8*)&p1; }
      bf16x8 bn[8];
      #pragma unroll
      for (int n = 0; n < 8; ++n)
        bn[n] = *(const bf16x8*)(bp + n*16*KE_ + k);
      #pragma unroll
      for (int m = 0; m < 2; ++m)
        #pragma unroll
        for (int n = 0; n < 8; ++n)
          acc[m][n] = __builtin_amdgcn_mfma_f32_16x16x32_bf16(am[m], bn[n], acc[m][n], 0, 0, 0);
    }
  }
  // conv K-step (k = 512..543), A directly from bf16 convf
  {
    bf16x8 am[2];
    am[0] = *(const bf16x8*)(convf + (row0 + fr)*NF_      + fk*8);
    am[1] = *(const bf16x8*)(convf + (row0 + 16 + fr)*NF_ + fk*8);
    bf16x8 bn[8];
    #pragma unroll
    for (int n = 0; n < 8; ++n)
      bn[n] = *(const bf16x8*)(bp + n*16*KE_ + E_ + fk*8);
    #pragma unroll
    for (int m = 0; m < 2; ++m)
      #pragma unroll
      for (int n = 0; n < 8; ++n)
        acc[m][n] = __builtin_amdgcn_mfma_f32_16x16x32_bf16(am[m], bn[n], acc[m][n], 0, 0, 0);
  }

  // epilogue: e[row] = sum_col v[col]*tanh(acc + q[b][col]); C: col=fr, row=fk*4+reg
  const float* qb = q + b*A_;
  float ep[2][4];
  #pragma unroll
  for (int m = 0; m < 2; ++m)
    #pragma unroll
    for (int r = 0; r < 4; ++r) ep[m][r] = 0.f;
  #pragma unroll
  for (int n = 0; n < 8; ++n) {
    int col = n*16 + fr;
    float qa = qb[col];
    float va = vvec[col];
    #pragma unroll
    for (int m = 0; m < 2; ++m)
      #pragma unroll
      for (int r = 0; r < 4; ++r)
        ep[m][r] = fmaf(va, tanh_fast(acc[m][n][r] + qa), ep[m][r]);
  }
  #pragma unroll
  for (int m = 0; m < 2; ++m)
    #pragma unroll
    for (int r = 0; r < 4; ++r) {
      float v = ep[m][r];
      v += __shfl_xor(v, 1); v += __shfl_xor(v, 2);
      v += __shfl_xor(v, 4); v += __shfl_xor(v, 8);
      if (fr == 0) epS[w*32 + m*16 + fk*4 + r] = v;
    }
  __syncthreads();
  // energies + per-block (max, sumexp) stats over the 128 rows
  float e = -1e30f;
  if (tid < 128) {
    e = epS[tid];
    energies[rowB + tid] = e;
  }
  float mx = e;
  #pragma unroll
  for (int o = 32; o > 0; o >>= 1) mx = fmaxf(mx, __shfl_xor(mx, o));
  if (lane == 0) redS[w] = mx;
  __syncthreads();
  mx = fmaxf(fmaxf(redS[0], redS[1]), fmaxf(redS[2], redS[3]));
  float sx = (tid < 128) ? __expf(e - mx) : 0.f;
  #pragma unroll
  for (int o = 32; o > 0; o >>= 1) sx += __shfl_xor(sx, o);
  __syncthreads();
  if (lane == 0) redS[w] = sx;
  __syncthreads();
  if (tid == 0) {
    stats[2*blockIdx.x]     = mx;
    stats[2*blockIdx.x + 1] = redS[0] + redS[1] + redS[2] + redS[3];
  }
}

// ---- softmax finalize + context: 32 blocks per batch, 64 rows each ----
__launch_bounds__(256)
__global__ void smctx_kernel(const float* __restrict__ memf, const float* __restrict__ energies,
                             const float* __restrict__ stats, float* __restrict__ outw,
                             float* __restrict__ ctx) {
  __shared__ float wS[64];
  const int blk = blockIdx.x;          // 2048
  const int b = blk >> 5;
  const int t0 = (blk & 31) * 64;
  const int tid = threadIdx.x;
  float M = -1e30f;
  #pragma unroll
  for (int j = 0; j < 16; ++j) M = fmaxf(M, stats[2*(b*16 + j)]);
  float Z = 0.f;
  #pragma unroll
  for (int j = 0; j < 16; ++j) Z += stats[2*(b*16 + j) + 1] * __expf(stats[2*(b*16 + j)] - M);
  const float invZ = 1.f / Z;
  if (tid < 64) {
    float w = __expf(energies[(long)b*T_ + t0 + tid] - M) * invZ;
    outw[(long)b*T_ + t0 + tid] = w;
    wS[tid] = w;
  }
  __syncthreads();
  const float* mb = memf + ((long)b*T_ + t0)*E_;
  float ax = 0.f, ay = 0.f;
  #pragma unroll 16
  for (int t = 0; t < 64; ++t) {
    float wt = wS[t];
    float2 m2 = *(const float2*)(mb + (long)t*E_ + tid*2);
    ax = fmaf(wt, m2.x, ax);
    ay = fmaf(wt, m2.y, ay);
  }
  atomicAdd(&ctx[b*E_ + tid*2],     ax);
  atomicAdd(&ctx[b*E_ + tid*2 + 1], ay);
}

extern "C" void kernel_launch(void* const* d_in, const int* in_sizes, int n_in,
                              void* d_out, int out_size, void* d_ws, size_t ws_size,
                              hipStream_t stream) {
  const float* query  = (const float*)d_in[0];
  const float* memory = (const float*)d_in[1];
  const float* awcat  = (const float*)d_in[2];
  const float* wq     = (const float*)d_in[3];
  const float* wmem   = (const float*)d_in[4];
  const float* convw  = (const float*)d_in[5];
  const float* wloc   = (const float*)d_in[6];
  const float* vvec   = (const float*)d_in[7];

  char* ws = (char*)d_ws;
  ushort* wcat    = (ushort*)(ws + OFF_WCAT);
  float*  qproj   = (float*)(ws + OFF_Q);
  float*  energies= (float*)(ws + OFF_EN);
  float*  stats   = (float*)(ws + OFF_ST);
  ushort* convf   = (ushort*)(ws + OFF_CF);

  float* ctx  = (float*)d_out;              // [64][512]
  float* outw = (float*)d_out + B_*E_;      // [64][2048]

  hipMemsetAsync(ctx, 0, B_*E_*sizeof(float), stream);
  prep_wcat<<<128, 256, 0, stream>>>(wmem, wloc, wcat);
  prep_q<<<64, 128, 0, stream>>>(query, wq, qproj);
  conv_kernel<<<2048, 256, 0, stream>>>(awcat, convw, convf);
  energy_kernel<<<1024, 256, 0, stream>>>(memory, convf, wcat, qproj, vvec,
                                          energies, stats);
  smctx_kernel<<<2048, 256, 0, stream>>>(memory, energies, stats, outw, ctx);
}